// Round 1
// 2181.624 us; speedup vs baseline: 1.7972x; 1.7972x over previous
//
#include <hip/hip_runtime.h>
#include <stdint.h>

#define SS   2048
#define DKK  64
#define NH   16
#define QT   64          // q rows per block
#define KT   64          // k cols per LDS tile
#define NT   (SS/KT)     // 32 k-tiles
#define TT   256         // 4 waves
#define EP   68          // e-tile padded stride (floats)

typedef float  f32x4 __attribute__((ext_vector_type(4)));
typedef short  s16x8 __attribute__((ext_vector_type(8)));
typedef unsigned int u32x2 __attribute__((ext_vector_type(2)));
typedef unsigned int u32x4 __attribute__((ext_vector_type(4)));

#define MF(a,b,c) __builtin_amdgcn_mfma_f32_16x16x32_bf16(a,b,c,0,0,0)
#define TRRD(d,a) asm volatile("ds_read_b64_tr_b16 %0, %1" : "=v"(d) : "v"(a))

static __device__ __forceinline__ unsigned bcu(float x){ return __builtin_bit_cast(unsigned, x); }
static __device__ __forceinline__ float    bcf(unsigned x){ return __builtin_bit_cast(float, x); }
// pack hi-bf16 (truncation) of (a,b) into one dword: low half = a, high half = b
static __device__ __forceinline__ unsigned pkhi(float a, float b){
  return (bcu(a)>>16) | (bcu(b)&0xffff0000u);
}
// 4 fp32 -> 4 bf16 hi + 4 bf16 lo (exact split: a = hi + lo with |lo| < ulp(hi))
static __device__ __forceinline__ void cvt4(float4 v, u32x2 &h, u32x2 &l){
  float xh=bcf(bcu(v.x)&0xffff0000u), yh=bcf(bcu(v.y)&0xffff0000u);
  float zh=bcf(bcu(v.z)&0xffff0000u), wh=bcf(bcu(v.w)&0xffff0000u);
  h[0]=pkhi(v.x,v.y); h[1]=pkhi(v.z,v.w);
  l[0]=pkhi(v.x-xh,v.y-yh); l[1]=pkhi(v.z-zh,v.w-wh);
}
// 8 fp32 -> hi/lo bf16 fragments (element j = k-index j, ascending)
static __device__ __forceinline__ void split8(const float f[8], s16x8 &h, s16x8 &l){
  u32x4 hu, lu;
  #pragma unroll
  for (int i=0;i<4;++i){
    float a=f[2*i], b=f[2*i+1];
    float ah=bcf(bcu(a)&0xffff0000u), bh_=bcf(bcu(b)&0xffff0000u);
    hu[i]=pkhi(a,b);
    lu[i]=pkhi(a-ah,b-bh_);
  }
  h=__builtin_bit_cast(s16x8,hu); l=__builtin_bit_cast(s16x8,lu);
}
static __device__ __forceinline__ s16x8 pk4(u32x2 a, u32x2 b){
  u32x4 t; t[0]=a[0]; t[1]=a[1]; t[2]=b[0]; t[3]=b[1];
  return __builtin_bit_cast(s16x8,t);
}
// K/V tile global loads: thread t covers rows (t>>4)+{0,16,32,48}, cols (t&15)*4..+3
static __device__ __forceinline__ void loadT(const float* __restrict__ B, int kt, int t, float4* f){
  const float* P = B + (size_t)kt*KT*DKK + (size_t)(t>>4)*DKK + (t&15)*4;
  #pragma unroll
  for (int i=0;i<4;++i) f[i] = *(const float4*)(P + i*16*DKK);
}
// K tile: row-major [k][64] bf16 hi/lo, XOR-swizzled (short-index ^= (k&7)<<3)
static __device__ __forceinline__ void stageK(unsigned short* Kh, unsigned short* Kl,
                                              int t, const float4* kf){
  const int dg = t & 15;
  #pragma unroll
  for (int i=0;i<4;++i){
    const int k = (t>>4) + i*16;
    u32x2 h,l; cvt4(kf[i],h,l);
    const int idx = (k*64 + dg*4) ^ ((k&7)<<3);
    *(u32x2*)&Kh[idx]=h; *(u32x2*)&Kl[idx]=l;
  }
}
// V tile: 16-col subtiled [dblk][k][16] bf16 hi/lo (ds_read_b64_tr_b16 layout)
static __device__ __forceinline__ void stageV(unsigned short* Vh, unsigned short* Vl,
                                              int t, const float4* vf){
  const int dg=t&15, db=dg>>2, ds=(dg&3)*4;
  #pragma unroll
  for (int i=0;i<4;++i){
    const int k=(t>>4)+i*16;
    u32x2 h,l; cvt4(vf[i],h,l);
    const int idx = db*1024 + k*16 + ds;
    *(u32x2*)&Vh[idx]=h; *(u32x2*)&Vl[idx]=l;
  }
}

__global__ __launch_bounds__(TT, 2) void attn_fwd(
    const float* __restrict__ Q, const float* __restrict__ K,
    const float* __restrict__ V, const int* __restrict__ M,
    float* __restrict__ outp, float* __restrict__ attn)
{
  __shared__ unsigned short Kh[KT*DKK], Kl[KT*DKK];   // 8KB + 8KB
  __shared__ unsigned short Vh[KT*DKK], Vl[KT*DKK];   // 8KB + 8KB
  __shared__ float et[QT*EP];                         // 17KB e-tile
  __shared__ unsigned mbits[QT*(SS/32)];              // 16KB mask bits
  __shared__ float zi[QT];

  // XCD-aware decode: 8 consecutive bh per XCD -> K/V stay in one XCD's L2
  const int p   = blockIdx.x;
  const int bh  = (p & 7) * 8 + ((p >> 3) >> 5);
  const int q0  = ((p >> 3) & 31) * QT;
  const int b   = bh >> 4;

  const int t    = threadIdx.x;
  const int lane = t & 63;
  const int wq   = t >> 6;      // wave id: owns q rows [wq*16, wq*16+16)
  const int c    = lane & 15;
  const int g    = lane >> 4;

  const float* Kb = K + (size_t)bh * SS * DKK;
  const float* Vb = V + (size_t)bh * SS * DKK;
  const int*   Mb = M + ((size_t)b * SS + q0) * SS;

  // ---- Q fragments in registers, pre-scaled by 1/sqrt(64), hi/lo split ----
  // A-frag: lane holds Q[q=l&15][d = ch*32 + g*8 + j]
  s16x8 qh[2], ql[2];
  {
    const float* Qr = Q + ((size_t)bh*SS + q0 + wq*16 + c) * DKK;
    #pragma unroll
    for (int ch=0; ch<2; ++ch){
      const float4 a = *(const float4*)(Qr + ch*32 + g*8);
      const float4 d = *(const float4*)(Qr + ch*32 + g*8 + 4);
      const float f[8] = {a.x*0.125f,a.y*0.125f,a.z*0.125f,a.w*0.125f,
                          d.x*0.125f,d.y*0.125f,d.z*0.125f,d.w*0.125f};
      split8(f, qh[ch], ql[ch]);
    }
  }

  // ---- phase 0: ballot-pack mask to bits (read 512KB int32 once -> 16KB) ----
  for (int i = wq; i < QT*(SS/64); i += 4){
    const int row = i >> 5;              // block-local q row
    const int kb  = (i & 31) << 6;       // k base (64 per iter)
    const int m   = Mb[(size_t)row*SS + kb + lane];
    const unsigned long long bb = __ballot(m != 0);
    if (lane == 0){
      mbits[row*64 + (kb>>5)    ] = (unsigned)bb;
      mbits[row*64 + (kb>>5) + 1] = (unsigned)(bb >> 32);
    }
  }
  __syncthreads();

  // ================= pass A: row sums Z =================
  float zr[4];
  {
    float zp[4] = {0.f,0.f,0.f,0.f};
    float4 kf[4];
    loadT(Kb, 0, t, kf);
    #pragma unroll 1
    for (int kt = 0; kt < NT; ++kt){
      stageK(Kh, Kl, t, kf);
      __syncthreads();
      if (kt + 1 < NT) loadT(Kb, kt+1, t, kf);        // prefetch under compute
      #pragma unroll
      for (int ct=0; ct<4; ++ct){
        const int rb = (ct*16 + c)*64, sw = (c&7)<<3, go = g*8;
        const s16x8 bh0 = *(const s16x8*)&Kh[(rb+go   ) ^ sw];
        const s16x8 bh1 = *(const s16x8*)&Kh[(rb+go+32) ^ sw];
        const s16x8 bl0 = *(const s16x8*)&Kl[(rb+go   ) ^ sw];
        const s16x8 bl1 = *(const s16x8*)&Kl[(rb+go+32) ^ sw];
        f32x4 cc = {0.f,0.f,0.f,0.f};
        __builtin_amdgcn_s_setprio(1);
        cc = MF(qh[0],bh0,cc); cc = MF(qh[1],bh1,cc);
        cc = MF(qh[0],bl0,cc); cc = MF(qh[1],bl1,cc);
        cc = MF(ql[0],bh0,cc); cc = MF(ql[1],bh1,cc);
        __builtin_amdgcn_s_setprio(0);
        const int wb = (wq*16 + 4*g)*64 + kt*2 + (ct>>1);
        const unsigned sh = ((ct&1)<<4) + c;
        #pragma unroll
        for (int r=0;r<4;++r){
          const unsigned mw = mbits[wb + r*64];
          const float ex = __expf(cc[r]);
          zp[r] += ((mw >> sh) & 1u) ? ex : 0.f;
        }
      }
      __syncthreads();
    }
    #pragma unroll
    for (int r=0;r<4;++r){
      float z = zp[r];
      z += __shfl_xor(z,1); z += __shfl_xor(z,2);
      z += __shfl_xor(z,4); z += __shfl_xor(z,8);
      zr[r] = 1.0f / z;                  // rows 4g+r (matches C/D + out frags)
    }
    if (c == 0){
      #pragma unroll
      for (int r=0;r<4;++r) zi[wq*16 + 4*g + r] = zr[r];
    }
  }

  // ================= pass B: recompute e, write attn, PV =================
  f32x4 acc[4] = {{0,0,0,0},{0,0,0,0},{0,0,0,0},{0,0,0,0}};
  {
    const unsigned vbH = (unsigned)(uintptr_t)(&Vh[0]) + c*8 + g*256;
    const unsigned vbL = (unsigned)(uintptr_t)(&Vl[0]) + c*8 + g*256;
    float4 kf[4], vf[4];
    loadT(Kb, 0, t, kf); loadT(Vb, 0, t, vf);
    #pragma unroll 1
    for (int kt = 0; kt < NT; ++kt){
      stageK(Kh,Kl,t,kf); stageV(Vh,Vl,t,vf);
      __syncthreads();
      if (kt+1 < NT){ loadT(Kb,kt+1,t,kf); loadT(Vb,kt+1,t,vf); }
      // ---- QK^T + mask + exp -> e-tile (bit-identical to pass A) ----
      #pragma unroll
      for (int ct=0; ct<4; ++ct){
        const int rb = (ct*16 + c)*64, sw = (c&7)<<3, go = g*8;
        const s16x8 bh0 = *(const s16x8*)&Kh[(rb+go   ) ^ sw];
        const s16x8 bh1 = *(const s16x8*)&Kh[(rb+go+32) ^ sw];
        const s16x8 bl0 = *(const s16x8*)&Kl[(rb+go   ) ^ sw];
        const s16x8 bl1 = *(const s16x8*)&Kl[(rb+go+32) ^ sw];
        f32x4 cc = {0.f,0.f,0.f,0.f};
        __builtin_amdgcn_s_setprio(1);
        cc = MF(qh[0],bh0,cc); cc = MF(qh[1],bh1,cc);
        cc = MF(qh[0],bl0,cc); cc = MF(qh[1],bl1,cc);
        cc = MF(ql[0],bh0,cc); cc = MF(ql[1],bh1,cc);
        __builtin_amdgcn_s_setprio(0);
        const int wb = (wq*16 + 4*g)*64 + kt*2 + (ct>>1);
        const unsigned sh = ((ct&1)<<4) + c;
        #pragma unroll
        for (int r=0;r<4;++r){
          const unsigned mw = mbits[wb + r*64];
          const float ex = __expf(cc[r]);
          et[(wq*16 + 4*g + r)*EP + ct*16 + c] = ((mw >> sh) & 1u) ? ex : 0.f;
        }
      }
      // ---- attn = e * zinv (wave-private rows; coalesced nontemporal f4) ----
      #pragma unroll
      for (int it=0; it<4; ++it){
        const int rl = it*4 + g;
        const float zv = zi[wq*16 + rl];
        f32x4 ev = *(const f32x4*)&et[(wq*16 + rl)*EP + c*4];
        ev *= zv;
        __builtin_nontemporal_store(ev,
          (f32x4*)&attn[((size_t)bh*SS + q0 + wq*16 + rl)*SS + kt*KT + c*4]);
      }
      // ---- P fragments: A[q=l&15][k=ch*32+g*8+j], hi/lo split ----
      s16x8 pah[2], pal[2];
      #pragma unroll
      for (int ch=0; ch<2; ++ch){
        const f32x4 p0 = *(const f32x4*)&et[(wq*16 + c)*EP + ch*32 + g*8];
        const f32x4 p1 = *(const f32x4*)&et[(wq*16 + c)*EP + ch*32 + g*8 + 4];
        const float pf[8] = {p0[0],p0[1],p0[2],p0[3],p1[0],p1[1],p1[2],p1[3]};
        split8(pf, pah[ch], pal[ch]);
      }
      // ---- PV: B-frags via hardware transpose read of subtiled V ----
      #pragma unroll
      for (int db=0; db<4; ++db){
        u32x2 h00,h01,h10,h11,l00,l01,l10,l11;
        const unsigned aH = vbH + db*2048, aL = vbL + db*2048;
        TRRD(h00,aH);      TRRD(h01,aH+128);
        TRRD(h10,aH+1024); TRRD(h11,aH+1152);
        TRRD(l00,aL);      TRRD(l01,aL+128);
        TRRD(l10,aL+1024); TRRD(l11,aL+1152);
        asm volatile("s_waitcnt lgkmcnt(0)");
        __builtin_amdgcn_sched_barrier(0);
        const s16x8 vh0 = pk4(h00,h01), vh1 = pk4(h10,h11);
        const s16x8 vl0 = pk4(l00,l01), vl1 = pk4(l10,l11);
        __builtin_amdgcn_s_setprio(1);
        acc[db] = MF(pah[0],vh0,acc[db]);
        acc[db] = MF(pah[1],vh1,acc[db]);
        acc[db] = MF(pal[0],vh0,acc[db]);
        acc[db] = MF(pal[1],vh1,acc[db]);
        acc[db] = MF(pah[0],vl0,acc[db]);
        acc[db] = MF(pah[1],vl1,acc[db]);
        __builtin_amdgcn_s_setprio(0);
      }
      __syncthreads();
    }
  }
  // ---- epilogue: out = acc * zinv ----
  #pragma unroll
  for (int db=0; db<4; ++db){
    #pragma unroll
    for (int r=0; r<4; ++r){
      outp[((size_t)bh*SS + q0 + wq*16 + 4*g + r)*DKK + db*16 + c] = acc[db][r]*zr[r];
    }
  }
}

extern "C" void kernel_launch(void* const* d_in, const int* in_sizes, int n_in,
                              void* d_out, int out_size, void* d_ws, size_t ws_size,
                              hipStream_t stream) {
  const float* Q = (const float*)d_in[0];
  const float* K = (const float*)d_in[1];
  const float* V = (const float*)d_in[2];
  const int*   M = (const int*)d_in[3];
  float* outp = (float*)d_out;
  float* attn = outp + (size_t)4 * NH * SS * DKK;   // out first, then attn
  dim3 grid(64 * (SS/QT));
  attn_fwd<<<grid, TT, 0, stream>>>(Q, K, V, M, outp, attn);
}

// Round 2
// 1584.337 us; speedup vs baseline: 2.4747x; 1.3770x over previous
//
#include <hip/hip_runtime.h>
#include <stdint.h>

#define SS   2048
#define DKK  64
#define NH   16
#define QT   128         // q rows per block
#define TT   512         // 8 waves
#define NTA  (SS/128)    // 16 pass-A k-tiles (128 rows each)
#define NTB  (SS/64)     // 32 pass-B k-tiles (64 rows each)
#define EP   68          // e-tile padded stride (floats)

typedef float  f32x4 __attribute__((ext_vector_type(4)));
typedef short  s16x8 __attribute__((ext_vector_type(8)));
typedef unsigned int u32x2 __attribute__((ext_vector_type(2)));
typedef unsigned int u32x4 __attribute__((ext_vector_type(4)));

#define MF(a,b,c) __builtin_amdgcn_mfma_f32_16x16x32_bf16(a,b,c,0,0,0)
#define TRRD(d,a) asm volatile("ds_read_b64_tr_b16 %0, %1" : "=v"(d) : "v"(a))

static __device__ __forceinline__ unsigned bcu(float x){ return __builtin_bit_cast(unsigned, x); }
static __device__ __forceinline__ float    bcf(unsigned x){ return __builtin_bit_cast(float, x); }
static __device__ __forceinline__ unsigned pkhi(float a, float b){
  return (bcu(a)>>16) | (bcu(b)&0xffff0000u);
}
// 4 fp32 -> 4 bf16 hi + 4 bf16 lo (exact split)
static __device__ __forceinline__ void cvt4(float4 v, u32x2 &h, u32x2 &l){
  float xh=bcf(bcu(v.x)&0xffff0000u), yh=bcf(bcu(v.y)&0xffff0000u);
  float zh=bcf(bcu(v.z)&0xffff0000u), wh=bcf(bcu(v.w)&0xffff0000u);
  h[0]=pkhi(v.x,v.y); h[1]=pkhi(v.z,v.w);
  l[0]=pkhi(v.x-xh,v.y-yh); l[1]=pkhi(v.z-zh,v.w-wh);
}
static __device__ __forceinline__ void split8(const float f[8], s16x8 &h, s16x8 &l){
  u32x4 hu, lu;
  #pragma unroll
  for (int i=0;i<4;++i){
    float a=f[2*i], b=f[2*i+1];
    float ah=bcf(bcu(a)&0xffff0000u), bh_=bcf(bcu(b)&0xffff0000u);
    hu[i]=pkhi(a,b);
    lu[i]=pkhi(a-ah,b-bh_);
  }
  h=__builtin_bit_cast(s16x8,hu); l=__builtin_bit_cast(s16x8,lu);
}
static __device__ __forceinline__ s16x8 pk4(u32x2 a, u32x2 b){
  u32x4 t; t[0]=a[0]; t[1]=a[1]; t[2]=b[0]; t[3]=b[1];
  return __builtin_bit_cast(s16x8,t);
}

// ---- staging (512 threads) ----
// pass-B K/V 64-row tile: thread t -> row k=t>>3, float4 cols (t&7), (t&7)+8
static __device__ __forceinline__ void load64(const float* __restrict__ B, int kt, int t, float4 f[2]){
  const float* P = B + (size_t)kt*64*DKK + (size_t)(t>>3)*DKK + (t&7)*4;
  f[0] = *(const float4*)P; f[1] = *(const float4*)(P+32);
}
static __device__ __forceinline__ void stageK64(unsigned short* Kh, unsigned short* Kl,
                                                int t, const float4 f[2]){
  const int k = t>>3, c0 = (t&7)*4, sw = (k&7)<<3;
  u32x2 h,l;
  cvt4(f[0],h,l); { const int i0=(k*64+c0   )^sw; *(u32x2*)&Kh[i0]=h; *(u32x2*)&Kl[i0]=l; }
  cvt4(f[1],h,l); { const int i1=(k*64+c0+32)^sw; *(u32x2*)&Kh[i1]=h; *(u32x2*)&Kl[i1]=l; }
}
// V tile: 16-col subtiled [db][k][16] (tr-read layout, verified)
static __device__ __forceinline__ void stageV64(unsigned short* Vh, unsigned short* Vl,
                                                int t, const float4 f[2]){
  const int k = t>>3, c0 = (t&7)*4, db0 = c0>>4, s0 = c0&15;
  u32x2 h,l;
  cvt4(f[0],h,l); { const int i0=db0*1024     + k*16 + s0; *(u32x2*)&Vh[i0]=h; *(u32x2*)&Vl[i0]=l; }
  cvt4(f[1],h,l); { const int i1=(db0+2)*1024 + k*16 + s0; *(u32x2*)&Vh[i1]=h; *(u32x2*)&Vl[i1]=l; }
}
// pass-A K 128-row tile: thread t -> row k=t>>2, float4 cols (t&3)+{0,4,8,12}
static __device__ __forceinline__ void load128(const float* __restrict__ B, int kt, int t, float4 f[4]){
  const float* P = B + (size_t)kt*128*DKK + (size_t)(t>>2)*DKK + (t&3)*4;
  #pragma unroll
  for (int i=0;i<4;++i) f[i] = *(const float4*)(P + i*16);
}
static __device__ __forceinline__ void stageK128(unsigned short* Kh, unsigned short* Kl,
                                                 int t, const float4 f[4]){
  const int k = t>>2, c0 = (t&3)*4, sw = (k&7)<<3;
  #pragma unroll
  for (int i=0;i<4;++i){
    u32x2 h,l; cvt4(f[i],h,l);
    const int idx = (k*64 + c0 + i*16) ^ sw;
    *(u32x2*)&Kh[idx]=h; *(u32x2*)&Kl[idx]=l;
  }
}

// ---- mask prepack: int32 mask -> bits in d_ws ----
__global__ __launch_bounds__(256) void pack_mask(const int* __restrict__ M,
                                                 unsigned* __restrict__ bits){
  const size_t NWAVE = (size_t)4*SS*SS/64;
  const int lane = threadIdx.x & 63;
  size_t w = (size_t)blockIdx.x*4 + (threadIdx.x>>6);
  const size_t step = (size_t)gridDim.x*4;
  for (; w < NWAVE; w += step){
    const int m = M[w*64 + lane];
    const unsigned long long bb = __ballot(m != 0);
    if (lane == 0){ bits[w*2] = (unsigned)bb; bits[w*2+1] = (unsigned)(bb>>32); }
  }
}

// MODE 1: mask bits prepacked in global.  MODE 0: direct int32 mask loads.
template<int MODE>
__global__ __launch_bounds__(TT, 4) void attn_fwd(
    const float* __restrict__ Q, const float* __restrict__ K,
    const float* __restrict__ V, const int* __restrict__ M,
    const unsigned* __restrict__ bits,
    float* __restrict__ outp, float* __restrict__ attn)
{
  __shared__ __align__(16) unsigned char smem[68096];
  unsigned short* KBh = (unsigned short*)smem;          // pass B: 8KB
  unsigned short* KBl = KBh + 64*64;                    // 8KB
  unsigned short* Vh  = KBl + 64*64;                    // 8KB
  unsigned short* Vl  = Vh  + 64*64;                    // 8KB
  unsigned short* KAh = (unsigned short*)smem;          // pass A: 16KB (overlaps V)
  unsigned short* KAl = KAh + 128*64;                   // 16KB
  float* et = (float*)(smem + 32768);                   // 34.8KB
  float* zi = (float*)(smem + 32768 + QT*EP*4);         // 512B

  // XCD-aware decode: 8 bh per XCD; all 16 q-blocks of a bh on one XCD
  const int p   = blockIdx.x;
  const int bh  = (p & 7) * 8 + ((p >> 3) >> 4);
  const int q0  = ((p >> 3) & 15) * QT;
  const int b   = bh >> 4;

  const int t    = threadIdx.x;
  const int lane = t & 63;
  const int wq   = t >> 6;      // wave id 0..7: owns q rows [wq*16, wq*16+16)
  const int c    = lane & 15;
  const int g    = lane >> 4;

  const float* Kb = K + (size_t)bh * SS * DKK;
  const float* Vb = V + (size_t)bh * SS * DKK;
  const int*   Mb = M + ((size_t)b * SS + q0) * SS;
  const size_t rowb = ((size_t)b * SS + q0 + wq*16 + 4*g) * (SS/32);  // bits row base

  // ---- Q fragments in registers (hi/lo split, pre-scaled) ----
  s16x8 qh[2], ql[2];
  {
    const float* Qr = Q + ((size_t)bh*SS + q0 + wq*16 + c) * DKK;
    #pragma unroll
    for (int ch=0; ch<2; ++ch){
      const float4 a = *(const float4*)(Qr + ch*32 + g*8);
      const float4 d = *(const float4*)(Qr + ch*32 + g*8 + 4);
      const float f[8] = {a.x*0.125f,a.y*0.125f,a.z*0.125f,a.w*0.125f,
                          d.x*0.125f,d.y*0.125f,d.z*0.125f,d.w*0.125f};
      split8(f, qh[ch], ql[ch]);
    }
  }

  // ================= pass A: row sums Z (128-row K tiles) =================
  float zr[4];
  {
    float zp[4] = {0.f,0.f,0.f,0.f};
    float4 kf[4];
    load128(Kb, 0, t, kf);
    #pragma unroll 1
    for (int kt = 0; kt < NTA; ++kt){
      stageK128(KAh, KAl, t, kf);
      __syncthreads();
      if (kt + 1 < NTA) load128(Kb, kt+1, t, kf);
      u32x4 mrow[4];
      if (MODE){
        #pragma unroll
        for (int r=0;r<4;++r) mrow[r] = *(const u32x4*)&bits[rowb + (size_t)r*(SS/32) + kt*4];
      }
      #pragma unroll
      for (int ct=0; ct<8; ++ct){
        const int rb = (ct*16 + c)*64, sw = (c&7)<<3, go = g*8;
        const s16x8 bh0 = *(const s16x8*)&KAh[(rb+go   ) ^ sw];
        const s16x8 bh1 = *(const s16x8*)&KAh[(rb+go+32) ^ sw];
        const s16x8 bl0 = *(const s16x8*)&KAl[(rb+go   ) ^ sw];
        const s16x8 bl1 = *(const s16x8*)&KAl[(rb+go+32) ^ sw];
        f32x4 cc = {0.f,0.f,0.f,0.f};
        __builtin_amdgcn_s_setprio(1);
        cc = MF(qh[0],bh0,cc); cc = MF(qh[1],bh1,cc);
        cc = MF(qh[0],bl0,cc); cc = MF(qh[1],bl1,cc);
        cc = MF(ql[0],bh0,cc); cc = MF(ql[1],bh1,cc);
        __builtin_amdgcn_s_setprio(0);
        const unsigned sh = ((ct&1)<<4) + c;
        #pragma unroll
        for (int r=0;r<4;++r){
          bool keep;
          if (MODE) keep = (mrow[r][ct>>1] >> sh) & 1u;
          else      keep = Mb[(size_t)(wq*16+4*g+r)*SS + kt*128 + ct*16 + c] != 0;
          const float ex = __expf(cc[r]);
          zp[r] += keep ? ex : 0.f;
        }
      }
      __syncthreads();
    }
    #pragma unroll
    for (int r=0;r<4;++r){
      float z = zp[r];
      z += __shfl_xor(z,1); z += __shfl_xor(z,2);
      z += __shfl_xor(z,4); z += __shfl_xor(z,8);
      zr[r] = 1.0f / z;
    }
    if (c == 0){
      #pragma unroll
      for (int r=0;r<4;++r) zi[wq*16 + 4*g + r] = zr[r];
    }
  }

  // ================= pass B: recompute e, write attn, PV =================
  f32x4 acc[4] = {{0,0,0,0},{0,0,0,0},{0,0,0,0},{0,0,0,0}};
  {
    const unsigned vbH = (unsigned)(uintptr_t)(&Vh[0]) + c*8 + g*256;
    const unsigned vbL = (unsigned)(uintptr_t)(&Vl[0]) + c*8 + g*256;
    float4 kf[2], vf[2];
    load64(Kb, 0, t, kf); load64(Vb, 0, t, vf);
    #pragma unroll 1
    for (int kt = 0; kt < NTB; ++kt){
      stageK64(KBh,KBl,t,kf); stageV64(Vh,Vl,t,vf);
      __syncthreads();
      if (kt+1 < NTB){ load64(Kb,kt+1,t,kf); load64(Vb,kt+1,t,vf); }
      u32x2 mrow[4];
      if (MODE){
        #pragma unroll
        for (int r=0;r<4;++r) mrow[r] = *(const u32x2*)&bits[rowb + (size_t)r*(SS/32) + kt*2];
      }
      // ---- QK^T + mask + exp -> e-tile (bit-identical to pass A) ----
      #pragma unroll
      for (int ct=0; ct<4; ++ct){
        const int rb = (ct*16 + c)*64, sw = (c&7)<<3, go = g*8;
        const s16x8 bh0 = *(const s16x8*)&KBh[(rb+go   ) ^ sw];
        const s16x8 bh1 = *(const s16x8*)&KBh[(rb+go+32) ^ sw];
        const s16x8 bl0 = *(const s16x8*)&KBl[(rb+go   ) ^ sw];
        const s16x8 bl1 = *(const s16x8*)&KBl[(rb+go+32) ^ sw];
        f32x4 cc = {0.f,0.f,0.f,0.f};
        __builtin_amdgcn_s_setprio(1);
        cc = MF(qh[0],bh0,cc); cc = MF(qh[1],bh1,cc);
        cc = MF(qh[0],bl0,cc); cc = MF(qh[1],bl1,cc);
        cc = MF(ql[0],bh0,cc); cc = MF(ql[1],bh1,cc);
        __builtin_amdgcn_s_setprio(0);
        const unsigned sh = ((ct&1)<<4) + c;
        #pragma unroll
        for (int r=0;r<4;++r){
          bool keep;
          if (MODE) keep = (mrow[r][ct>>1] >> sh) & 1u;
          else      keep = Mb[(size_t)(wq*16+4*g+r)*SS + kt*64 + ct*16 + c] != 0;
          const float ex = __expf(cc[r]);
          et[(wq*16 + 4*g + r)*EP + ct*16 + c] = keep ? ex : 0.f;
        }
      }
      // ---- attn = e * zinv ----
      #pragma unroll
      for (int it=0; it<4; ++it){
        const int rl = it*4 + g;
        const float zv = zi[wq*16 + rl];
        f32x4 ev = *(const f32x4*)&et[(wq*16 + rl)*EP + c*4];
        ev *= zv;
        __builtin_nontemporal_store(ev,
          (f32x4*)&attn[((size_t)bh*SS + q0 + wq*16 + rl)*SS + kt*64 + c*4]);
      }
      // ---- P fragments ----
      s16x8 pah[2], pal[2];
      #pragma unroll
      for (int ch=0; ch<2; ++ch){
        const f32x4 p0 = *(const f32x4*)&et[(wq*16 + c)*EP + ch*32 + g*8];
        const f32x4 p1 = *(const f32x4*)&et[(wq*16 + c)*EP + ch*32 + g*8 + 4];
        const float pf[8] = {p0[0],p0[1],p0[2],p0[3],p1[0],p1[1],p1[2],p1[3]};
        split8(pf, pah[ch], pal[ch]);
      }
      // ---- PV via hardware transpose read (layout verified) ----
      #pragma unroll
      for (int db=0; db<4; ++db){
        u32x2 h00,h01,h10,h11,l00,l01,l10,l11;
        const unsigned aH = vbH + db*2048, aL = vbL + db*2048;
        TRRD(h00,aH);      TRRD(h01,aH+128);
        TRRD(h10,aH+1024); TRRD(h11,aH+1152);
        TRRD(l00,aL);      TRRD(l01,aL+128);
        TRRD(l10,aL+1024); TRRD(l11,aL+1152);
        asm volatile("s_waitcnt lgkmcnt(0)");
        __builtin_amdgcn_sched_barrier(0);
        const s16x8 vh0 = pk4(h00,h01), vh1 = pk4(h10,h11);
        const s16x8 vl0 = pk4(l00,l01), vl1 = pk4(l10,l11);
        __builtin_amdgcn_s_setprio(1);
        acc[db] = MF(pah[0],vh0,acc[db]);
        acc[db] = MF(pah[1],vh1,acc[db]);
        acc[db] = MF(pal[0],vh0,acc[db]);
        acc[db] = MF(pal[1],vh1,acc[db]);
        acc[db] = MF(pah[0],vl0,acc[db]);
        acc[db] = MF(pah[1],vl1,acc[db]);
        __builtin_amdgcn_s_setprio(0);
      }
      __syncthreads();
    }
  }
  // ---- epilogue ----
  #pragma unroll
  for (int db=0; db<4; ++db){
    #pragma unroll
    for (int r=0; r<4; ++r){
      outp[((size_t)bh*SS + q0 + wq*16 + 4*g + r)*DKK + db*16 + c] = acc[db][r]*zr[r];
    }
  }
}

extern "C" void kernel_launch(void* const* d_in, const int* in_sizes, int n_in,
                              void* d_out, int out_size, void* d_ws, size_t ws_size,
                              hipStream_t stream) {
  const float* Q = (const float*)d_in[0];
  const float* K = (const float*)d_in[1];
  const float* V = (const float*)d_in[2];
  const int*   M = (const int*)d_in[3];
  float* outp = (float*)d_out;
  float* attn = outp + (size_t)4 * NH * SS * DKK;   // out first, then attn
  dim3 grid(64 * (SS/QT));                          // 1024 blocks
  const size_t need = (size_t)4 * SS * (SS/32) * sizeof(unsigned);   // 2 MB
  if (d_ws != nullptr && ws_size >= need){
    unsigned* bits = (unsigned*)d_ws;
    pack_mask<<<1024, 256, 0, stream>>>(M, bits);
    attn_fwd<1><<<grid, TT, 0, stream>>>(Q, K, V, M, bits, outp, attn);
  } else {
    attn_fwd<0><<<grid, TT, 0, stream>>>(Q, K, V, M, nullptr, outp, attn);
  }
}